// Round 1
// baseline (2200.261 us; speedup 1.0000x reference)
//
#include <hip/hip_runtime.h>
#include <math.h>

// MultiHeadAttention fp32 baseline for MI355X (gfx950).
// x[4,2048,1024] fp32; Wq/Wk/Wv/Wo [1024,1024] (out,in); biases [1024].
// Pipeline: 3x proj GEMM -> flash attention -> output GEMM.
// All fp32 vector math (no MFMA yet): correctness-first baseline.

#define SEQ     2048
#define EMB     1024
#define NBATCH  4
#define NHEADS  16
#define HDIM    64
#define MROWS   (NBATCH*SEQ)   // 8192

// ---------------------------------------------------------------------------
// GEMM: Y = A @ W^T + bias.  A:[M][1024] row-major, W:[1024][1024] (out,in).
// SCATTER=1: write to [N,H,S,D] layout; SCATTER=0: plain [M][1024].
// Tile 128x128, BK=8, 256 threads, 8x8 micro-tile per thread.
// ---------------------------------------------------------------------------
template<int SCATTER>
__global__ __launch_bounds__(256)
void gemm_xwt(const float* __restrict__ A, const float* __restrict__ W,
              const float* __restrict__ bias, float* __restrict__ Y)
{
    __shared__ __align__(16) float As[8][128];   // k-major
    __shared__ __align__(16) float Bs[8][128];   // k-major
    const int t  = threadIdx.x;
    const int bm = blockIdx.y * 128;
    const int bn = blockIdx.x * 128;
    const int lr = t >> 1;        // 0..127 : tile row loaded by this thread
    const int lh = t & 1;         // which half (4 floats) of the 8-wide k slab
    const int ty = t >> 4;        // 0..15
    const int tx = t & 15;        // 0..15

    float acc[8][8];
#pragma unroll
    for (int i = 0; i < 8; ++i)
#pragma unroll
        for (int j = 0; j < 8; ++j) acc[i][j] = 0.f;

    const float* Arow = A + (size_t)(bm + lr) * EMB + lh * 4;
    const float* Wrow = W + (size_t)(bn + lr) * EMB + lh * 4;

    for (int k0 = 0; k0 < EMB; k0 += 8) {
        const float4 a4 = *(const float4*)(Arow + k0);
        const float4 w4 = *(const float4*)(Wrow + k0);
        __syncthreads();             // protect prior iteration's LDS reads
        As[lh*4+0][lr] = a4.x; As[lh*4+1][lr] = a4.y;
        As[lh*4+2][lr] = a4.z; As[lh*4+3][lr] = a4.w;
        Bs[lh*4+0][lr] = w4.x; Bs[lh*4+1][lr] = w4.y;
        Bs[lh*4+2][lr] = w4.z; Bs[lh*4+3][lr] = w4.w;
        __syncthreads();
#pragma unroll
        for (int kk = 0; kk < 8; ++kk) {
            const float4 a0 = *(const float4*)&As[kk][ty*8];
            const float4 a1 = *(const float4*)&As[kk][ty*8+4];
            const float4 b0 = *(const float4*)&Bs[kk][tx*8];
            const float4 b1 = *(const float4*)&Bs[kk][tx*8+4];
            const float av[8] = {a0.x,a0.y,a0.z,a0.w,a1.x,a1.y,a1.z,a1.w};
            const float bv[8] = {b0.x,b0.y,b0.z,b0.w,b1.x,b1.y,b1.z,b1.w};
#pragma unroll
            for (int i = 0; i < 8; ++i)
#pragma unroll
                for (int j = 0; j < 8; ++j)
                    acc[i][j] = fmaf(av[i], bv[j], acc[i][j]);
        }
    }

#pragma unroll
    for (int i = 0; i < 8; ++i) {
        const int m = bm + ty*8 + i;
#pragma unroll
        for (int jj = 0; jj < 2; ++jj) {
            const int c = bn + tx*8 + jj*4;
            const float4 b4 = *(const float4*)&bias[c];
            float4 o;
            o.x = acc[i][jj*4+0] + b4.x;
            o.y = acc[i][jj*4+1] + b4.y;
            o.z = acc[i][jj*4+2] + b4.z;
            o.w = acc[i][jj*4+3] + b4.w;
            size_t idx;
            if (SCATTER) {
                const int n = m >> 11, s = m & (SEQ-1);
                const int h = c >> 6, d = c & (HDIM-1);
                idx = (((size_t)n*NHEADS + h)*SEQ + s)*HDIM + d;
            } else {
                idx = (size_t)m*EMB + c;
            }
            *(float4*)&Y[idx] = o;
        }
    }
}

// ---------------------------------------------------------------------------
// Flash attention, fp32.  Q/K/V in [N,H,S,D].  Output -> [N,S,E].
// One block = 32 q-rows of one (n,h). 256 threads (4 waves), each wave owns
// 8 q-rows (intra-wave online softmax, no cross-wave reduction needed).
// K/V tiles of 64 keys staged in LDS (row pad 64->68 to break bank aliasing).
// ---------------------------------------------------------------------------
__global__ __launch_bounds__(256)
void attn_flash(const float* __restrict__ Q, const float* __restrict__ K,
                const float* __restrict__ V, float* __restrict__ Og)
{
    __shared__ __align__(16) float Qs[32][68];
    __shared__ __align__(16) float Ks[64][68];
    __shared__ __align__(16) float Vs[64][68];
    __shared__ __align__(16) float Ps[32][68];
    __shared__ float m_s[32], l_s[32], sc_s[32];

    const int t  = threadIdx.x;
    const int nh = blockIdx.y;           // n*NHEADS + h
    const int q0 = blockIdx.x * 32;
    const float* Qb = Q + (size_t)nh * SEQ * HDIM;
    const float* Kb = K + (size_t)nh * SEQ * HDIM;
    const float* Vb = V + (size_t)nh * SEQ * HDIM;

    // load Q tile: 32x64 floats = 512 float4, 2 per thread
#pragma unroll
    for (int i = 0; i < 2; ++i) {
        const int idx = i*256 + t;
        const int rr = idx >> 4, c4 = idx & 15;
        *(float4*)&Qs[rr][c4*4] = *(const float4*)&Qb[(size_t)(q0+rr)*HDIM + c4*4];
    }
    if (t < 32) { m_s[t] = -1e30f; l_s[t] = 0.f; }

    const int jg = (t & 31) * 2;        // key pair base (QK) / d pair base (PV)
    const int rg = (t >> 5) * 4;        // 4-row group base: 0,4,...,28
    const int r0 = (t >> 6) * 8;        // wave's 8-row base (for final write)
    (void)r0;

    float Oacc[4][2];
#pragma unroll
    for (int i = 0; i < 4; ++i) { Oacc[i][0] = 0.f; Oacc[i][1] = 0.f; }

    for (int kt = 0; kt < SEQ/64; ++kt) {
        __syncthreads();   // prior tile's Ps/Vs reads done before overwrite
        // stage K,V tile (64x64 each): 1024 float4 each, 4 per thread
#pragma unroll
        for (int i = 0; i < 4; ++i) {
            const int idx = i*256 + t;
            const int rr = idx >> 4, c4 = idx & 15;
            const size_t g = (size_t)(kt*64+rr)*HDIM + c4*4;
            *(float4*)&Ks[rr][c4*4] = *(const float4*)&Kb[g];
            *(float4*)&Vs[rr][c4*4] = *(const float4*)&Vb[g];
        }
        __syncthreads();

        // ---- QK^T : 4 rows x 2 keys per thread ----
        float sc[4][2];
#pragma unroll
        for (int i = 0; i < 4; ++i) { sc[i][0] = 0.f; sc[i][1] = 0.f; }
#pragma unroll
        for (int d4 = 0; d4 < 16; ++d4) {
            const float4 ka = *(const float4*)&Ks[jg  ][d4*4];
            const float4 kb = *(const float4*)&Ks[jg+1][d4*4];
#pragma unroll
            for (int i = 0; i < 4; ++i) {
                const float4 q = *(const float4*)&Qs[rg+i][d4*4];
                sc[i][0] = fmaf(q.x,ka.x, fmaf(q.y,ka.y, fmaf(q.z,ka.z, fmaf(q.w,ka.w, sc[i][0]))));
                sc[i][1] = fmaf(q.x,kb.x, fmaf(q.y,kb.y, fmaf(q.z,kb.z, fmaf(q.w,kb.w, sc[i][1]))));
            }
        }
#pragma unroll
        for (int i = 0; i < 4; ++i) {
            float2 s2; s2.x = sc[i][0]*0.125f; s2.y = sc[i][1]*0.125f;
            *(float2*)&Ps[rg+i][jg] = s2;
        }
        __syncthreads();

        // ---- online softmax (8 lanes per row, intra-wave) ----
        {
            const int rr = t >> 3, ll = t & 7;
            float mx = -1e30f;
#pragma unroll
            for (int j = 0; j < 8; ++j) mx = fmaxf(mx, Ps[rr][ll*8+j]);
            mx = fmaxf(mx, __shfl_xor(mx, 1));
            mx = fmaxf(mx, __shfl_xor(mx, 2));
            mx = fmaxf(mx, __shfl_xor(mx, 4));
            const float m_old = m_s[rr];
            const float m_new = fmaxf(m_old, mx);
            float sum = 0.f;
#pragma unroll
            for (int j = 0; j < 8; ++j) {
                const float p = __expf(Ps[rr][ll*8+j] - m_new);
                Ps[rr][ll*8+j] = p;
                sum += p;
            }
            sum += __shfl_xor(sum, 1);
            sum += __shfl_xor(sum, 2);
            sum += __shfl_xor(sum, 4);
            if (ll == 0) {
                const float rs = __expf(m_old - m_new);
                sc_s[rr] = rs;
                m_s[rr]  = m_new;
                l_s[rr]  = l_s[rr]*rs + sum;
            }
        }
        __syncthreads();

        // ---- PV : 4 rows x 2 d-columns per thread ----
#pragma unroll
        for (int i = 0; i < 4; ++i) {
            const float rs = sc_s[rg+i];
            Oacc[i][0] *= rs; Oacc[i][1] *= rs;
        }
#pragma unroll
        for (int j4 = 0; j4 < 16; ++j4) {
            float2 v2[4];
#pragma unroll
            for (int jj = 0; jj < 4; ++jj)
                v2[jj] = *(const float2*)&Vs[j4*4+jj][jg];
#pragma unroll
            for (int i = 0; i < 4; ++i) {
                const float4 p = *(const float4*)&Ps[rg+i][j4*4];
                Oacc[i][0] = fmaf(p.x,v2[0].x, fmaf(p.y,v2[1].x, fmaf(p.z,v2[2].x, fmaf(p.w,v2[3].x, Oacc[i][0]))));
                Oacc[i][1] = fmaf(p.x,v2[0].y, fmaf(p.y,v2[1].y, fmaf(p.z,v2[2].y, fmaf(p.w,v2[3].y, Oacc[i][1]))));
            }
        }
    }

    // final write: out[n][s][h*64+d], normalized by l
    const int nn = nh >> 4, hh = nh & 15;
#pragma unroll
    for (int i = 0; i < 4; ++i) {
        const float invl = 1.f / l_s[rg+i];
        float2 o2; o2.x = Oacc[i][0]*invl; o2.y = Oacc[i][1]*invl;
        *(float2*)&Og[((size_t)nn*SEQ + (q0+rg+i))*EMB + hh*HDIM + jg] = o2;
    }
}

// ---------------------------------------------------------------------------
extern "C" void kernel_launch(void* const* d_in, const int* in_sizes, int n_in,
                              void* d_out, int out_size, void* d_ws, size_t ws_size,
                              hipStream_t stream)
{
    const float* x  = (const float*)d_in[0];
    const float* Wq = (const float*)d_in[1];
    const float* bq = (const float*)d_in[2];
    const float* Wk = (const float*)d_in[3];
    const float* bk = (const float*)d_in[4];
    const float* Wv = (const float*)d_in[5];
    const float* bv = (const float*)d_in[6];
    const float* Wo = (const float*)d_in[7];
    const float* bo = (const float*)d_in[8];

    float* ws = (float*)d_ws;
    const size_t buf = (size_t)MROWS * EMB;   // 8.39M floats = 32 MiB
    float* Qb = ws;
    float* Kb = Qb + buf;
    float* Vb = Kb + buf;
    float* Ob = Vb + buf;                     // total 128 MiB of workspace

    const dim3 gGemm(EMB/128, MROWS/128);     // (8, 64)
    const dim3 blk(256);

    gemm_xwt<1><<<gGemm, blk, 0, stream>>>(x,  Wq, bq, Qb);
    gemm_xwt<1><<<gGemm, blk, 0, stream>>>(x,  Wk, bk, Kb);
    gemm_xwt<1><<<gGemm, blk, 0, stream>>>(x,  Wv, bv, Vb);

    attn_flash<<<dim3(SEQ/32, NBATCH*NHEADS), blk, 0, stream>>>(Qb, Kb, Vb, Ob);

    gemm_xwt<0><<<gGemm, blk, 0, stream>>>(Ob, Wo, bo, (float*)d_out);
}

// Round 2
// 712.938 us; speedup vs baseline: 3.0862x; 3.0862x over previous
//
#include <hip/hip_runtime.h>
#include <math.h>

// MultiHeadAttention, split-bf16 MFMA pipeline for MI355X (gfx950).
// Every fp32 operand is split into bf16 hi (top 16 bits, truncated) + bf16 lo
// (residual, ~2^-16 rel).  Each GEMM product uses 3 MFMAs: hi*hi + hi*lo + lo*hi.
// Pipeline: split x/W -> 3 proj GEMMs (V written transposed) -> flash attn
// (MFMA QK^T + in-register softmax + MFMA PV) -> output GEMM.

#define SEQ 2048
#define EMB 1024
#define NB  4
#define NH  16
#define HD  64
#define MR  (NB*SEQ)   // 8192

typedef __attribute__((ext_vector_type(8))) short bf8;   // 8 bf16 (A/B frag)
typedef __attribute__((ext_vector_type(4))) float f4;    // 4 f32  (C/D frag)
typedef unsigned short u16;
typedef unsigned int   u32;

#define MFMA(a,b,c) __builtin_amdgcn_mfma_f32_16x16x32_bf16(a,b,c,0,0,0)

__device__ __forceinline__ void split1(float x, u16& h, u16& l) {
    u32 u = __float_as_uint(x);
    h = (u16)(u >> 16);                                   // truncated bf16 hi
    float r = x - __uint_as_float(u & 0xffff0000u);       // exact residual
    l = (u16)(__float_as_uint(r) >> 16);                  // bf16 lo
}

// ---------------------------------------------------------------------------
// fp32 -> (bf16 hi, bf16 lo) split, vectorized x4.
// ---------------------------------------------------------------------------
__global__ __launch_bounds__(256)
void split2(const float* __restrict__ src, u16* __restrict__ hi,
            u16* __restrict__ lo, int n4)
{
    int i = blockIdx.x * 256 + threadIdx.x;
    if (i >= n4) return;
    float4 f = ((const float4*)src)[i];
    ushort4 h, l;
    split1(f.x, h.x, l.x); split1(f.y, h.y, l.y);
    split1(f.z, h.z, l.z); split1(f.w, h.w, l.w);
    ((ushort4*)hi)[i] = h;
    ((ushort4*)lo)[i] = l;
}

// ---------------------------------------------------------------------------
// Split-bf16 GEMM: Y = A @ W^T + bias.  A,W given as hi/lo bf16 pairs,
// both row-major [rows][1024].  Tile 128x128, BK=32, 4 waves of 64x64.
// SCATTER: 0 -> plain [M][1024] fp32; 1 -> [N,H,S,D] fp32; 2 -> [N,H,D,S] fp32.
// A-frag: lane holds A[l&15][(l>>4)*8+i]; B-frag: lane holds W[l&15][(l>>4)*8+i]
// (row-major gather identical for both since B = W^T of row-major W).
// C/D: row=(l>>4)*4+j, col=l&15  [verified layout].
// ---------------------------------------------------------------------------
template<int SCATTER>
__global__ __launch_bounds__(256)
void gemm_split(const u16* __restrict__ Ahi, const u16* __restrict__ Alo,
                const u16* __restrict__ Whi, const u16* __restrict__ Wlo,
                const float* __restrict__ bias, float* __restrict__ Y)
{
    __shared__ u16 As[2][128][40];   // [hi/lo][row][k] pad 32->40 (80B rows)
    __shared__ u16 Bs[2][128][40];

    const int t  = threadIdx.x;
    const int bm = blockIdx.y * 128, bn = blockIdx.x * 128;
    const int w  = t >> 6, lane = t & 63;
    const int wr = w >> 1, wc = w & 1;
    const int r  = lane & 15, g = lane >> 4;

    f4 acc[4][4];
#pragma unroll
    for (int i = 0; i < 4; ++i)
#pragma unroll
        for (int j = 0; j < 4; ++j)
#pragma unroll
            for (int e = 0; e < 4; ++e) acc[i][j][e] = 0.f;

    for (int k0 = 0; k0 < EMB; k0 += 32) {
        __syncthreads();
#pragma unroll
        for (int p = 0; p < 2; ++p) {
            const int idx = p * 256 + t;
            const int row = idx >> 2, c8 = (idx & 3) * 8;
            *(uint4*)&As[0][row][c8] = *(const uint4*)&Ahi[(size_t)(bm+row)*EMB + k0 + c8];
            *(uint4*)&As[1][row][c8] = *(const uint4*)&Alo[(size_t)(bm+row)*EMB + k0 + c8];
            *(uint4*)&Bs[0][row][c8] = *(const uint4*)&Whi[(size_t)(bn+row)*EMB + k0 + c8];
            *(uint4*)&Bs[1][row][c8] = *(const uint4*)&Wlo[(size_t)(bn+row)*EMB + k0 + c8];
        }
        __syncthreads();

        bf8 ah[4], al[4];
#pragma unroll
        for (int mi = 0; mi < 4; ++mi) {
            ah[mi] = *(const bf8*)&As[0][wr*64 + mi*16 + r][g*8];
            al[mi] = *(const bf8*)&As[1][wr*64 + mi*16 + r][g*8];
        }
#pragma unroll
        for (int ni = 0; ni < 4; ++ni) {
            const bf8 bh = *(const bf8*)&Bs[0][wc*64 + ni*16 + r][g*8];
            const bf8 bl = *(const bf8*)&Bs[1][wc*64 + ni*16 + r][g*8];
#pragma unroll
            for (int mi = 0; mi < 4; ++mi) {
                acc[mi][ni] = MFMA(al[mi], bh, acc[mi][ni]);
                acc[mi][ni] = MFMA(ah[mi], bl, acc[mi][ni]);
                acc[mi][ni] = MFMA(ah[mi], bh, acc[mi][ni]);
            }
        }
    }

    // epilogue
#pragma unroll
    for (int mi = 0; mi < 4; ++mi) {
        const int m = bm + wr*64 + mi*16 + g*4;      // + j
#pragma unroll
        for (int ni = 0; ni < 4; ++ni) {
            const int c = bn + wc*64 + ni*16 + r;
            const float b = bias[c];
            if (SCATTER == 2) {
                // V^T: [N,H,D,S]; j runs along s -> contiguous float4
                const int n = m >> 11, s = m & (SEQ-1);
                const int h = c >> 6, d = c & (HD-1);
                float4 st;
                st.x = acc[mi][ni][0] + b; st.y = acc[mi][ni][1] + b;
                st.z = acc[mi][ni][2] + b; st.w = acc[mi][ni][3] + b;
                *(float4*)&Y[(((size_t)n*NH + h)*HD + d)*SEQ + s] = st;
            } else {
#pragma unroll
                for (int j = 0; j < 4; ++j) {
                    const int mm = m + j;
                    const float v = acc[mi][ni][j] + b;
                    size_t idx;
                    if (SCATTER == 1) {
                        const int n = mm >> 11, s = mm & (SEQ-1);
                        const int h = c >> 6, d = c & (HD-1);
                        idx = (((size_t)n*NH + h)*SEQ + s)*HD + d;
                    } else {
                        idx = (size_t)mm*EMB + c;
                    }
                    Y[idx] = v;
                }
            }
        }
    }
}

// ---------------------------------------------------------------------------
// Flash attention with split-bf16 MFMA.
// Q,K fp32 [N,H,S,D]; V fp32 TRANSPOSED [N,H,D,S]. Output: split bf16 hi/lo
// [N,S,E] feeding the final GEMM.  Block = 128 q-rows (4 waves x 32 rows),
// KV tile = 64.  Q pre-scaled by 1/8, split, held in registers.
// Softmax fully in C-fragment registers (16-lane shfl_xor row reduction).
// P packed (hi | lo<<16) into per-wave u32 LDS, re-read as A-fragments.
// ---------------------------------------------------------------------------
__global__ __launch_bounds__(256)
void attn_mfma(const float* __restrict__ Qf, const float* __restrict__ Kf,
               const float* __restrict__ Vtf,
               u16* __restrict__ Ohi, u16* __restrict__ Olo)
{
    __shared__ u16 KsH[64][72], KsL[64][72];   // K tile  [kv][d], pad 72
    __shared__ u16 VtH[64][72], VtL[64][72];   // V^T tile [d][kv], pad 72
    __shared__ u32 Pu[4][32][68];              // per-wave P (hi|lo<<16), pad 68

    const int t = threadIdx.x, w = t >> 6, lane = t & 63;
    const int r = lane & 15, g = lane >> 4;
    const int nh = blockIdx.y;
    const int q0 = blockIdx.x * 128;
    const int qw = q0 + w * 32;
    const float* Qb = Qf  + (size_t)nh * SEQ * HD;
    const float* Kb = Kf  + (size_t)nh * SEQ * HD;
    const float* Vb = Vtf + (size_t)nh * HD * SEQ;

    // ---- Q fragments (scaled by 0.125), hi/lo, in registers ----
    bf8 qh[2][2], ql[2][2];
#pragma unroll
    for (int mi = 0; mi < 2; ++mi)
#pragma unroll
        for (int c = 0; c < 2; ++c) {
            const float* src = Qb + (size_t)(qw + mi*16 + r)*HD + c*32 + g*8;
            const float4 f0 = *(const float4*)src;
            const float4 f1 = *(const float4*)(src + 4);
            const float ff[8] = {f0.x,f0.y,f0.z,f0.w,f1.x,f1.y,f1.z,f1.w};
            bf8 h, l;
#pragma unroll
            for (int i = 0; i < 8; ++i) {
                u16 hh, ll; split1(ff[i]*0.125f, hh, ll);
                h[i] = (short)hh; l[i] = (short)ll;
            }
            qh[mi][c] = h; ql[mi][c] = l;
        }

    f4 oacc[2][4];
    float mrow[2][4], lrow[2][4];
#pragma unroll
    for (int mi = 0; mi < 2; ++mi)
#pragma unroll
        for (int j = 0; j < 4; ++j) {
            mrow[mi][j] = -1e30f; lrow[mi][j] = 0.f;
#pragma unroll
            for (int df = 0; df < 4; ++df) oacc[mi][df][j] = 0.f;
        }

    for (int kt = 0; kt < SEQ/64; ++kt) {
        const int kv0 = kt * 64;
        __syncthreads();
        // ---- stage K and V^T tiles, splitting fp32 -> bf16 hi/lo ----
#pragma unroll
        for (int p = 0; p < 4; ++p) {
            const int idx = p * 256 + t;
            const int row = idx >> 4, c4 = (idx & 15) * 4;
            const float4 kf = *(const float4*)&Kb[(size_t)(kv0+row)*HD + c4];
            ushort4 h, l;
            split1(kf.x,h.x,l.x); split1(kf.y,h.y,l.y);
            split1(kf.z,h.z,l.z); split1(kf.w,h.w,l.w);
            *(ushort4*)&KsH[row][c4] = h;
            *(ushort4*)&KsL[row][c4] = l;
            const float4 vf = *(const float4*)&Vb[(size_t)row*SEQ + kv0 + c4];
            split1(vf.x,h.x,l.x); split1(vf.y,h.y,l.y);
            split1(vf.z,h.z,l.z); split1(vf.w,h.w,l.w);
            *(ushort4*)&VtH[row][c4] = h;
            *(ushort4*)&VtL[row][c4] = l;
        }
        __syncthreads();

        // ---- QK^T: S[mi][kf] (scaled; Q carries 1/8) ----
        f4 s[2][4];
#pragma unroll
        for (int mi = 0; mi < 2; ++mi)
#pragma unroll
            for (int kf = 0; kf < 4; ++kf)
#pragma unroll
                for (int e = 0; e < 4; ++e) s[mi][kf][e] = 0.f;
#pragma unroll
        for (int kf = 0; kf < 4; ++kf) {
#pragma unroll
            for (int c = 0; c < 2; ++c) {
                const bf8 kh = *(const bf8*)&KsH[kf*16 + r][c*32 + g*8];
                const bf8 kl = *(const bf8*)&KsL[kf*16 + r][c*32 + g*8];
#pragma unroll
                for (int mi = 0; mi < 2; ++mi) {
                    s[mi][kf] = MFMA(ql[mi][c], kh, s[mi][kf]);
                    s[mi][kf] = MFMA(qh[mi][c], kl, s[mi][kf]);
                    s[mi][kf] = MFMA(qh[mi][c], kh, s[mi][kf]);
                }
            }
        }

        // ---- online softmax in C-fragment registers ----
#pragma unroll
        for (int mi = 0; mi < 2; ++mi)
#pragma unroll
            for (int j = 0; j < 4; ++j) {
                float mx = fmaxf(fmaxf(s[mi][0][j], s[mi][1][j]),
                                 fmaxf(s[mi][2][j], s[mi][3][j]));
                mx = fmaxf(mx, __shfl_xor(mx, 1));
                mx = fmaxf(mx, __shfl_xor(mx, 2));
                mx = fmaxf(mx, __shfl_xor(mx, 4));
                mx = fmaxf(mx, __shfl_xor(mx, 8));
                const float mold = mrow[mi][j];
                const float mnew = fmaxf(mold, mx);
                const float corr = __expf(mold - mnew);
                mrow[mi][j] = mnew;
                float sum = 0.f;
#pragma unroll
                for (int kf = 0; kf < 4; ++kf) {
                    const float p = __expf(s[mi][kf][j] - mnew);
                    s[mi][kf][j] = p;
                    sum += p;
                }
                sum += __shfl_xor(sum, 1); sum += __shfl_xor(sum, 2);
                sum += __shfl_xor(sum, 4); sum += __shfl_xor(sum, 8);
                lrow[mi][j] = lrow[mi][j]*corr + sum;
#pragma unroll
                for (int df = 0; df < 4; ++df) oacc[mi][df][j] *= corr;
            }

        // ---- pack P (hi | lo<<16) into per-wave LDS ----
#pragma unroll
        for (int mi = 0; mi < 2; ++mi)
#pragma unroll
            for (int kf = 0; kf < 4; ++kf)
#pragma unroll
                for (int j = 0; j < 4; ++j) {
                    u16 hh, ll; split1(s[mi][kf][j], hh, ll);
                    Pu[w][mi*16 + g*4 + j][kf*16 + r] = (u32)hh | ((u32)ll << 16);
                }

        // ---- PV: O += P @ V ----
#pragma unroll
        for (int c = 0; c < 2; ++c) {
            bf8 ph[2], pl[2];
#pragma unroll
            for (int mi = 0; mi < 2; ++mi) {
                const uint4 a = *(const uint4*)&Pu[w][mi*16 + r][c*32 + g*8];
                const uint4 b = *(const uint4*)&Pu[w][mi*16 + r][c*32 + g*8 + 4];
                const u32 uu[8] = {a.x,a.y,a.z,a.w,b.x,b.y,b.z,b.w};
                bf8 h, l;
#pragma unroll
                for (int i = 0; i < 8; ++i) {
                    h[i] = (short)(uu[i] & 0xffffu);
                    l[i] = (short)(uu[i] >> 16);
                }
                ph[mi] = h; pl[mi] = l;
            }
#pragma unroll
            for (int df = 0; df < 4; ++df) {
                const bf8 vh = *(const bf8*)&VtH[df*16 + r][c*32 + g*8];
                const bf8 vl = *(const bf8*)&VtL[df*16 + r][c*32 + g*8];
#pragma unroll
                for (int mi = 0; mi < 2; ++mi) {
                    oacc[mi][df] = MFMA(pl[mi], vh, oacc[mi][df]);
                    oacc[mi][df] = MFMA(ph[mi], vl, oacc[mi][df]);
                    oacc[mi][df] = MFMA(ph[mi], vh, oacc[mi][df]);
                }
            }
        }
    }

    // ---- epilogue: normalize, split, write [N,S,E] ----
    const int n = nh >> 4, h = nh & 15;
#pragma unroll
    for (int mi = 0; mi < 2; ++mi)
#pragma unroll
        for (int j = 0; j < 4; ++j) {
            const float inv = 1.0f / lrow[mi][j];
            const int srow = qw + mi*16 + g*4 + j;
            const size_t base = ((size_t)n*SEQ + srow)*EMB + h*HD;
#pragma unroll
            for (int df = 0; df < 4; ++df) {
                const float v = oacc[mi][df][j] * inv;
                u16 hh, ll; split1(v, hh, ll);
                Ohi[base + df*16 + r] = hh;
                Olo[base + df*16 + r] = ll;
            }
        }
}

// ---------------------------------------------------------------------------
extern "C" void kernel_launch(void* const* d_in, const int* in_sizes, int n_in,
                              void* d_out, int out_size, void* d_ws, size_t ws_size,
                              hipStream_t stream)
{
    const float* x  = (const float*)d_in[0];
    const float* Wq = (const float*)d_in[1];
    const float* bq = (const float*)d_in[2];
    const float* Wk = (const float*)d_in[3];
    const float* bk = (const float*)d_in[4];
    const float* Wv = (const float*)d_in[5];
    const float* bv = (const float*)d_in[6];
    const float* Wo = (const float*)d_in[7];
    const float* bo = (const float*)d_in[8];

    const size_t MB = (size_t)1 << 20;
    char* W = (char*)d_ws;
    u16* xhi = (u16*)(W + 0);          // 16 MB   (later reused as Ohi)
    u16* xlo = (u16*)(W + 16*MB);      // 16 MB   (later reused as Olo)
    u16* wsp = (u16*)(W + 32*MB);      // 8 x 2 MB: q/k/v/o hi,lo
    float* Qf = (float*)(W + 48*MB);   // 32 MB [N,H,S,D]
    float* Kf = (float*)(W + 80*MB);   // 32 MB [N,H,S,D]
    float* Vt = (float*)(W + 112*MB);  // 32 MB [N,H,D,S]
    const size_t WN = 1048576;         // elements per W split array
    u16 *wqh = wsp,        *wql = wsp + WN;
    u16 *wkh = wsp + 2*WN, *wkl = wsp + 3*WN;
    u16 *wvh = wsp + 4*WN, *wvl = wsp + 5*WN;
    u16 *woh = wsp + 6*WN, *wol = wsp + 7*WN;
    u16 *ohi = xhi, *olo = xlo;

    // splits
    split2<<<dim3(MR*EMB/4/256), dim3(256), 0, stream>>>(x,  xhi, xlo, MR*EMB/4);
    split2<<<dim3(WN/4/256),     dim3(256), 0, stream>>>(Wq, wqh, wql, WN/4);
    split2<<<dim3(WN/4/256),     dim3(256), 0, stream>>>(Wk, wkh, wkl, WN/4);
    split2<<<dim3(WN/4/256),     dim3(256), 0, stream>>>(Wv, wvh, wvl, WN/4);
    split2<<<dim3(WN/4/256),     dim3(256), 0, stream>>>(Wo, woh, wol, WN/4);

    const dim3 gG(EMB/128, MR/128), blk(256);
    gemm_split<1><<<gG, blk, 0, stream>>>(xhi, xlo, wqh, wql, bq, Qf);
    gemm_split<1><<<gG, blk, 0, stream>>>(xhi, xlo, wkh, wkl, bk, Kf);
    gemm_split<2><<<gG, blk, 0, stream>>>(xhi, xlo, wvh, wvl, bv, Vt);

    attn_mfma<<<dim3(SEQ/128, NB*NH), blk, 0, stream>>>(Qf, Kf, Vt, ohi, olo);

    gemm_split<0><<<gG, blk, 0, stream>>>(ohi, olo, woh, wol, bo, (float*)d_out);
}